// Round 1
// baseline (225.736 us; speedup 1.0000x reference)
//
#include <hip/hip_runtime.h>

#define LOG2E 1.44269504088896340736f

typedef _Float16 half8 __attribute__((ext_vector_type(8)));
typedef _Float16 half4_t __attribute__((ext_vector_type(4)));
typedef float f32x4 __attribute__((ext_vector_type(4)));

__device__ __forceinline__ void gld16(const void* g, void* l) {
  __builtin_amdgcn_global_load_lds(
      (const __attribute__((address_space(1))) void*)g,
      (__attribute__((address_space(3))) void*)l, 16, 0, 0);
}

// ---------------- fp32 -> fp16 conversion ----------------
__global__ void cvt_f32_f16(const float* __restrict__ src, _Float16* __restrict__ dst, int n4) {
  int i = blockIdx.x * blockDim.x + threadIdx.x;
  int st = gridDim.x * blockDim.x;
  for (; i < n4; i += st) {
    float4 v = reinterpret_cast<const float4*>(src)[i];
    half4_t h;
    h[0] = (_Float16)v.x; h[1] = (_Float16)v.y; h[2] = (_Float16)v.z; h[3] = (_Float16)v.w;
    reinterpret_cast<half4_t*>(dst)[i] = h;
  }
}

// ---------------- QKV projection GEMM ----------------
// C[m][n] = sum_k X[m][k] * W[n][k]  (out = X @ W^T), M=8192, N=768, K=768
// mode 0: q -> [b][h][s][d]; mode 1: k -> same; mode 2: v -> transposed [b][h][d][s]
__global__ __launch_bounds__(256) void qkv_gemm(
    const _Float16* __restrict__ X,
    const _Float16* __restrict__ Wq, const _Float16* __restrict__ Wk, const _Float16* __restrict__ Wv,
    const float* __restrict__ bq, const float* __restrict__ bk, const float* __restrict__ bv,
    _Float16* __restrict__ qo, _Float16* __restrict__ ko, _Float16* __restrict__ vo) {
  __shared__ _Float16 Al[2][128 * 32];
  __shared__ _Float16 Bl[2][128 * 32];
  const int tid = threadIdx.x;
  const int lane = tid & 63, w = tid >> 6;
  const int wr = w >> 1, wc = w & 1;
  const int mt = blockIdx.x, ntl = blockIdx.y, mode = blockIdx.z;
  const _Float16* W = (mode == 0) ? Wq : (mode == 1) ? Wk : Wv;
  const float* bias = (mode == 0) ? bq : (mode == 1) ? bk : bv;
  _Float16* out = (mode == 0) ? qo : (mode == 1) ? ko : vo;

  const _Float16* Xb = X + (size_t)mt * 128 * 768;
  const _Float16* Wb = W + (size_t)ntl * 128 * 768;

  const f32x4 zero4 = {0.f, 0.f, 0.f, 0.f};
  f32x4 acc[4][4];
#pragma unroll
  for (int i = 0; i < 4; ++i)
#pragma unroll
    for (int j = 0; j < 4; ++j) acc[i][j] = zero4;

  auto stage = [&](int bufi, int kt) {
#pragma unroll
    for (int it = 0; it < 2; ++it) {
      int ci = tid + it * 256;
      int row = ci >> 2, c = ci & 3;
      int sw = ((c ^ ((row >> 1) & 3)) << 4);  // swizzled 16B chunk within 64B row
      gld16((const char*)(Xb + row * 768) + kt * 64 + sw, (char*)&Al[bufi][0] + ci * 16);
      gld16((const char*)(Wb + row * 768) + kt * 64 + sw, (char*)&Bl[bufi][0] + ci * 16);
    }
  };

  stage(0, 0);
  __syncthreads();
  int buf = 0;
  for (int kt = 0; kt < 24; ++kt) {
    if (kt + 1 < 24) stage(buf ^ 1, kt + 1);
    half8 af[4], bf[4];
#pragma unroll
    for (int mi = 0; mi < 4; ++mi) {
      int row = wr * 64 + mi * 16 + (lane & 15);
      int cc = (lane >> 4) ^ ((row >> 1) & 3);
      af[mi] = *(const half8*)((const char*)&Al[buf][0] + row * 64 + cc * 16);
    }
#pragma unroll
    for (int ni = 0; ni < 4; ++ni) {
      int row = wc * 64 + ni * 16 + (lane & 15);
      int cc = (lane >> 4) ^ ((row >> 1) & 3);
      bf[ni] = *(const half8*)((const char*)&Bl[buf][0] + row * 64 + cc * 16);
    }
#pragma unroll
    for (int mi = 0; mi < 4; ++mi)
#pragma unroll
      for (int ni = 0; ni < 4; ++ni)
        acc[mi][ni] = __builtin_amdgcn_mfma_f32_16x16x32_f16(af[mi], bf[ni], acc[mi][ni], 0, 0, 0);
    __syncthreads();
    buf ^= 1;
  }

  const int m0 = mt * 128 + wr * 64, n0 = ntl * 128 + wc * 64;
#pragma unroll
  for (int ni = 0; ni < 4; ++ni) {
    int n = n0 + ni * 16 + (lane & 15);
    float bvv = bias[n];
    int h = n >> 6, d = n & 63;
#pragma unroll
    for (int mi = 0; mi < 4; ++mi) {
      int m = m0 + mi * 16 + ((lane >> 4) << 2);
      int b = m >> 11, s = m & 2047;
      if (mode < 2) {
        _Float16* dst = out + (((size_t)(b * 12 + h) * 2048 + s) * 64 + d);
#pragma unroll
        for (int r = 0; r < 4; ++r) dst[(size_t)r * 64] = (_Float16)(acc[mi][ni][r] + bvv);
      } else {
        half4_t pk;
#pragma unroll
        for (int r = 0; r < 4; ++r) pk[r] = (_Float16)(acc[mi][ni][r] + bvv);
        *(half4_t*)(out + ((size_t)(b * 12 + h) * 64 + d) * 2048 + s) = pk;
      }
    }
  }
}

// ---------------- flash attention ----------------
// grid: (32 q-tiles, 48 b*h). 4 waves/block, wave owns 16 q-rows. KVBLK=64.
__global__ __launch_bounds__(256) void flash_attn(
    const _Float16* __restrict__ qb, const _Float16* __restrict__ kbuf,
    const _Float16* __restrict__ vtb, const float* __restrict__ mask,
    const float* __restrict__ head_bias, float* __restrict__ out) {
  __shared__ _Float16 Kl[64 * 64];
  __shared__ _Float16 Vl[64 * 64];
  __shared__ _Float16 Pl[4][16][72];

  const int tid = threadIdx.x;
  const int lane = tid & 63, w = tid >> 6;
  const int qt = blockIdx.x, bh = blockIdx.y;
  const int b = bh / 12, h = bh % 12;
  const int q0 = qt * 64 + w * 16;

  const _Float16* Kg = kbuf + (size_t)bh * 2048 * 64;
  const _Float16* Vg = vtb + (size_t)bh * 64 * 2048;

  const _Float16* qptr = qb + ((size_t)bh * 2048 + q0 + (lane & 15)) * 64 + ((lane >> 4) << 3);
  half8 qa0 = *(const half8*)qptr;
  half8 qa1 = *(const half8*)(qptr + 32);

  const float hb2 = 0.5f * head_bias[h] * LOG2E;
  const float scl = 0.125f * LOG2E;
  const float* mrow = mask + (size_t)b * 2048;

  const f32x4 zero4 = {0.f, 0.f, 0.f, 0.f};
  f32x4 o[4];
  float m_[4], l_[4];
#pragma unroll
  for (int r = 0; r < 4; ++r) { o[r] = zero4; m_[r] = -1e30f; l_[r] = 0.f; }

  for (int kb0 = 0; kb0 < 2048; kb0 += 64) {
    {  // stage K[64 s][64 d] and V^T[64 d][64 s] with XOR-swizzled source (linear LDS dest)
      const char* ks = (const char*)(Kg + (size_t)kb0 * 64);
      const char* vs = (const char*)(Vg + kb0);
#pragma unroll
      for (int it = 0; it < 2; ++it) {
        int ci = tid + it * 256;
        int row = ci >> 3, c = ci & 7;
        int sw = ((c ^ (row & 7)) << 4);
        gld16(ks + row * 128 + sw, (char*)Kl + ci * 16);
        gld16(vs + (size_t)row * 4096 + sw, (char*)Vl + ci * 16);
      }
    }
    __syncthreads();

    // QK^T: D[q][kpos], 4 k-subtiles of 16
    f32x4 sc4[4];
#pragma unroll
    for (int t = 0; t < 4; ++t) {
      int row = t * 16 + (lane & 15);
      int c0 = (((lane >> 4)) ^ (row & 7)) << 4;
      int c1 = (((lane >> 4) + 4) ^ (row & 7)) << 4;
      half8 k0 = *(const half8*)((const char*)Kl + row * 128 + c0);
      half8 k1 = *(const half8*)((const char*)Kl + row * 128 + c1);
      f32x4 z = zero4;
      z = __builtin_amdgcn_mfma_f32_16x16x32_f16(qa0, k0, z, 0, 0, 0);
      z = __builtin_amdgcn_mfma_f32_16x16x32_f16(qa1, k1, z, 0, 0, 0);
      sc4[t] = z;
    }

    float mk[4];
#pragma unroll
    for (int t = 0; t < 4; ++t) {
      float mval = mrow[kb0 + t * 16 + (lane & 15)];
      mk[t] = hb2 + (1.f - mval) * (-10000.f * LOG2E);
    }
#pragma unroll
    for (int t = 0; t < 4; ++t)
#pragma unroll
      for (int r = 0; r < 4; ++r) sc4[t][r] = sc4[t][r] * scl + mk[t];

    // wave-parallel online softmax (log2 domain); q-row r lives in 16-lane group
    float mx[4], fc[4], rs[4];
#pragma unroll
    for (int r = 0; r < 4; ++r)
      mx[r] = fmaxf(fmaxf(sc4[0][r], sc4[1][r]), fmaxf(sc4[2][r], sc4[3][r]));
#pragma unroll
    for (int i = 1; i <= 8; i <<= 1)
#pragma unroll
      for (int r = 0; r < 4; ++r) mx[r] = fmaxf(mx[r], __shfl_xor(mx[r], i, 64));
#pragma unroll
    for (int r = 0; r < 4; ++r) {
      float mn = fmaxf(m_[r], mx[r]);
      fc[r] = __builtin_amdgcn_exp2f(m_[r] - mn);
      m_[r] = mn;
    }
#pragma unroll
    for (int t = 0; t < 4; ++t)
#pragma unroll
      for (int r = 0; r < 4; ++r) sc4[t][r] = __builtin_amdgcn_exp2f(sc4[t][r] - m_[r]);
#pragma unroll
    for (int r = 0; r < 4; ++r) rs[r] = (sc4[0][r] + sc4[1][r]) + (sc4[2][r] + sc4[3][r]);
#pragma unroll
    for (int i = 1; i <= 8; i <<= 1)
#pragma unroll
      for (int r = 0; r < 4; ++r) rs[r] += __shfl_xor(rs[r], i, 64);
#pragma unroll
    for (int r = 0; r < 4; ++r) l_[r] = l_[r] * fc[r] + rs[r];

    // P (acc layout) -> LDS, per-wave buffer; rescale O
#pragma unroll
    for (int t = 0; t < 4; ++t)
#pragma unroll
      for (int r = 0; r < 4; ++r)
        Pl[w][((lane >> 4) << 2) + r][t * 16 + (lane & 15)] = (_Float16)sc4[t][r];
#pragma unroll
    for (int d4 = 0; d4 < 4; ++d4)
#pragma unroll
      for (int r = 0; r < 4; ++r) o[d4][r] *= fc[r];
    __syncthreads();  // cross-lane P visibility

    // PV: A = P[q][k] from Pl, B = V[k][d] from Vl (=V^T rows)
    const char* pw = (const char*)&Pl[w][0][0];
    half8 pa0 = *(const half8*)(pw + (lane & 15) * 144 + ((lane >> 4) << 4));
    half8 pa1 = *(const half8*)(pw + (lane & 15) * 144 + 64 + ((lane >> 4) << 4));
#pragma unroll
    for (int d4 = 0; d4 < 4; ++d4) {
      int row = d4 * 16 + (lane & 15);
      int c0 = (((lane >> 4)) ^ (row & 7)) << 4;
      int c1 = (((lane >> 4) + 4) ^ (row & 7)) << 4;
      half8 v0 = *(const half8*)((const char*)Vl + row * 128 + c0);
      half8 v1 = *(const half8*)((const char*)Vl + row * 128 + c1);
      o[d4] = __builtin_amdgcn_mfma_f32_16x16x32_f16(pa0, v0, o[d4], 0, 0, 0);
      o[d4] = __builtin_amdgcn_mfma_f32_16x16x32_f16(pa1, v1, o[d4], 0, 0, 0);
    }
    __syncthreads();  // all reads of Kl/Vl done before restage
  }

  float inv[4];
#pragma unroll
  for (int r = 0; r < 4; ++r) inv[r] = 1.f / l_[r];
  int srow = q0 + ((lane >> 4) << 2);
  float* op = out + ((size_t)(b * 2048) + srow) * 768 + h * 64 + (lane & 15);
#pragma unroll
  for (int d4 = 0; d4 < 4; ++d4)
#pragma unroll
    for (int r = 0; r < 4; ++r) op[(size_t)r * 768 + d4 * 16] = o[d4][r] * inv[r];
}

extern "C" void kernel_launch(void* const* d_in, const int* in_sizes, int n_in,
                              void* d_out, int out_size, void* d_ws, size_t ws_size,
                              hipStream_t stream) {
  const float* hidden = (const float*)d_in[0];
  const float* mask = (const float*)d_in[1];
  const float* Wq = (const float*)d_in[2];
  const float* bq = (const float*)d_in[3];
  const float* Wk = (const float*)d_in[4];
  const float* bk = (const float*)d_in[5];
  const float* Wv = (const float*)d_in[6];
  const float* bv = (const float*)d_in[7];
  const float* hbias = (const float*)d_in[8];
  float* out = (float*)d_out;

  char* ws = (char*)d_ws;
  _Float16* hb   = (_Float16*)(ws);               // [8192][768]           12,582,912 B
  _Float16* wqb  = (_Float16*)(ws + 12582912);    // [768][768]             1,179,648 B
  _Float16* wkb  = (_Float16*)(ws + 13762560);
  _Float16* wvb  = (_Float16*)(ws + 14942208);
  _Float16* qbuf = (_Float16*)(ws + 16121856);    // [48][2048][64]
  _Float16* kbuf = (_Float16*)(ws + 28704768);    // [48][2048][64]
  _Float16* vtb  = (_Float16*)(ws + 41287680);    // [48][64][2048]

  cvt_f32_f16<<<dim3(1024), dim3(256), 0, stream>>>(hidden, hb, 6291456 / 4);
  cvt_f32_f16<<<dim3(288), dim3(256), 0, stream>>>(Wq, wqb, 589824 / 4);
  cvt_f32_f16<<<dim3(288), dim3(256), 0, stream>>>(Wk, wkb, 589824 / 4);
  cvt_f32_f16<<<dim3(288), dim3(256), 0, stream>>>(Wv, wvb, 589824 / 4);

  qkv_gemm<<<dim3(64, 6, 3), dim3(256), 0, stream>>>(hb, wqb, wkb, wvb, bq, bk, bv,
                                                     qbuf, kbuf, vtb);
  flash_attn<<<dim3(32, 48), dim3(256), 0, stream>>>(qbuf, kbuf, vtb, mask, hbias, out);
}

// Round 2
// 191.156 us; speedup vs baseline: 1.1809x; 1.1809x over previous
//
#include <hip/hip_runtime.h>

#define LOG2E 1.44269504088896340736f
#define QSCALE 0.18033688011112042f  // 0.125 * LOG2E, folded into Q at projection
#define THR 8.0f                     // defer-max threshold (log2 domain)

typedef _Float16 half8 __attribute__((ext_vector_type(8)));
typedef _Float16 half4_t __attribute__((ext_vector_type(4)));
typedef __fp16 fp16x2 __attribute__((ext_vector_type(2)));
typedef float f32x4 __attribute__((ext_vector_type(4)));

__device__ __forceinline__ void gld16(const void* g, void* l) {
  __builtin_amdgcn_global_load_lds(
      (const __attribute__((address_space(1))) void*)g,
      (__attribute__((address_space(3))) void*)l, 16, 0, 0);
}

// ---------------- fp32 -> fp16 conversion ----------------
__global__ void cvt_f32_f16(const float* __restrict__ src, _Float16* __restrict__ dst, int n4) {
  int i = blockIdx.x * blockDim.x + threadIdx.x;
  int st = gridDim.x * blockDim.x;
  for (; i < n4; i += st) {
    float4 v = reinterpret_cast<const float4*>(src)[i];
    half4_t h;
    h[0] = (_Float16)v.x; h[1] = (_Float16)v.y; h[2] = (_Float16)v.z; h[3] = (_Float16)v.w;
    reinterpret_cast<half4_t*>(dst)[i] = h;
  }
}

// mask term in log2 domain: mk[b][k] = (1-mask)*(-10000*log2e)
__global__ void prep_mask(const float* __restrict__ mask, float* __restrict__ mkb, int n) {
  int i = blockIdx.x * blockDim.x + threadIdx.x;
  if (i < n) mkb[i] = (1.0f - mask[i]) * (-10000.0f * LOG2E);
}

// ---------------- QKV projection GEMM ----------------
// mode 0: q (pre-scaled by QSCALE) -> [b][h][s][d]; mode 1: k -> same; mode 2: v -> [b][h][d][s]
__global__ __launch_bounds__(256) void qkv_gemm(
    const _Float16* __restrict__ X,
    const _Float16* __restrict__ Wq, const _Float16* __restrict__ Wk, const _Float16* __restrict__ Wv,
    const float* __restrict__ bq, const float* __restrict__ bk, const float* __restrict__ bv,
    _Float16* __restrict__ qo, _Float16* __restrict__ ko, _Float16* __restrict__ vo) {
  __shared__ _Float16 Al[2][128 * 32];
  __shared__ _Float16 Bl[2][128 * 32];
  const int tid = threadIdx.x;
  const int lane = tid & 63, w = tid >> 6;
  const int wr = w >> 1, wc = w & 1;
  const int mt = blockIdx.x, ntl = blockIdx.y, mode = blockIdx.z;
  const _Float16* W = (mode == 0) ? Wq : (mode == 1) ? Wk : Wv;
  const float* bias = (mode == 0) ? bq : (mode == 1) ? bk : bv;
  _Float16* out = (mode == 0) ? qo : (mode == 1) ? ko : vo;
  const float oscale = (mode == 0) ? QSCALE : 1.0f;

  const _Float16* Xb = X + (size_t)mt * 128 * 768;
  const _Float16* Wb = W + (size_t)ntl * 128 * 768;

  const f32x4 zero4 = {0.f, 0.f, 0.f, 0.f};
  f32x4 acc[4][4];
#pragma unroll
  for (int i = 0; i < 4; ++i)
#pragma unroll
    for (int j = 0; j < 4; ++j) acc[i][j] = zero4;

  auto stage = [&](int bufi, int kt) {
#pragma unroll
    for (int it = 0; it < 2; ++it) {
      int ci = tid + it * 256;
      int row = ci >> 2, c = ci & 3;
      int sw = ((c ^ ((row >> 1) & 3)) << 4);
      gld16((const char*)(Xb + row * 768) + kt * 64 + sw, (char*)&Al[bufi][0] + ci * 16);
      gld16((const char*)(Wb + row * 768) + kt * 64 + sw, (char*)&Bl[bufi][0] + ci * 16);
    }
  };

  stage(0, 0);
  __syncthreads();
  int buf = 0;
  for (int kt = 0; kt < 24; ++kt) {
    if (kt + 1 < 24) stage(buf ^ 1, kt + 1);
    half8 af[4], bf[4];
#pragma unroll
    for (int mi = 0; mi < 4; ++mi) {
      int row = wr * 64 + mi * 16 + (lane & 15);
      int cc = (lane >> 4) ^ ((row >> 1) & 3);
      af[mi] = *(const half8*)((const char*)&Al[buf][0] + row * 64 + cc * 16);
    }
#pragma unroll
    for (int ni = 0; ni < 4; ++ni) {
      int row = wc * 64 + ni * 16 + (lane & 15);
      int cc = (lane >> 4) ^ ((row >> 1) & 3);
      bf[ni] = *(const half8*)((const char*)&Bl[buf][0] + row * 64 + cc * 16);
    }
#pragma unroll
    for (int mi = 0; mi < 4; ++mi)
#pragma unroll
      for (int ni = 0; ni < 4; ++ni)
        acc[mi][ni] = __builtin_amdgcn_mfma_f32_16x16x32_f16(af[mi], bf[ni], acc[mi][ni], 0, 0, 0);
    __syncthreads();
    buf ^= 1;
  }

  const int m0 = mt * 128 + wr * 64, n0 = ntl * 128 + wc * 64;
#pragma unroll
  for (int ni = 0; ni < 4; ++ni) {
    int n = n0 + ni * 16 + (lane & 15);
    float bvv = bias[n];
    int h = n >> 6, d = n & 63;
#pragma unroll
    for (int mi = 0; mi < 4; ++mi) {
      int m = m0 + mi * 16 + ((lane >> 4) << 2);
      int b = m >> 11, s = m & 2047;
      if (mode < 2) {
        _Float16* dst = out + (((size_t)(b * 12 + h) * 2048 + s) * 64 + d);
#pragma unroll
        for (int r = 0; r < 4; ++r) dst[(size_t)r * 64] = (_Float16)((acc[mi][ni][r] + bvv) * oscale);
      } else {
        half4_t pk;
#pragma unroll
        for (int r = 0; r < 4; ++r) pk[r] = (_Float16)(acc[mi][ni][r] + bvv);
        *(half4_t*)(out + ((size_t)(b * 12 + h) * 64 + d) * 2048 + s) = pk;
      }
    }
  }
}

// ---------------- flash attention (swapped QK^T, 1 barrier/iter) ----------------
// grid: 768 blocks (XCD-bijective decode), 4 waves/block, wave owns 32 q-rows (2 frags).
// D_qk[k][q] = mfma(K_frag, Q_frag): lane(hi,lo) holds k = t*16+hi*4+r, q = f*16+lo.
__global__ __launch_bounds__(256) void flash_attn(
    const _Float16* __restrict__ qb, const _Float16* __restrict__ kbuf,
    const _Float16* __restrict__ vtb, const float* __restrict__ mkb,
    float* __restrict__ out) {
  __shared__ _Float16 Kl[2][64 * 64];
  __shared__ _Float16 Vl[2][64 * 64];
  __shared__ _Float16 Pl[8][16 * 64];  // [w*2+f][q][k], XOR-swizzled rows

  const int tid = threadIdx.x;
  const int lane = tid & 63, w = tid >> 6;
  const int hi = lane >> 4, lo = lane & 15;

  // XCD-bijective: all 16 q-tiles of one bh land on one XCD (round-robin assumption)
  const int i = blockIdx.x;
  const int bh = (i & 7) + 8 * ((i >> 3) >> 4);
  const int qt = (i >> 3) & 15;
  const int b = bh / 12, h = bh % 12;
  const int q0w = qt * 128 + w * 32;

  const _Float16* Kg = kbuf + (size_t)bh * 2048 * 64;
  const _Float16* Vg = vtb + (size_t)bh * 64 * 2048;
  const float* mkrow = mkb + (size_t)b * 2048;

  // Q fragments (B-operand layout): qa[f][half] = Q[q0w+f*16+lo][half*32 + hi*8 ..+8]
  half8 qa[2][2];
#pragma unroll
  for (int f = 0; f < 2; ++f) {
    const _Float16* qp = qb + ((size_t)bh * 2048 + q0w + f * 16 + lo) * 64 + hi * 8;
    qa[f][0] = *(const half8*)qp;
    qa[f][1] = *(const half8*)(qp + 32);
  }

  auto stage = [&](int nb, int t) {
#pragma unroll
    for (int it = 0; it < 2; ++it) {
      int ci = tid + it * 256;
      int row = ci >> 3, c = ci & 7;
      int sw = ((c ^ (row & 7)) << 4);
      gld16((const char*)Kg + (size_t)t * 8192 + row * 128 + sw, (char*)&Kl[nb][0] + ci * 16);
      gld16((const char*)Vg + (size_t)row * 4096 + t * 128 + sw, (char*)&Vl[nb][0] + ci * 16);
    }
  };

  const f32x4 zero4 = {0.f, 0.f, 0.f, 0.f};
  f32x4 o[2][4];
  float m_[2], l_[2];
#pragma unroll
  for (int f = 0; f < 2; ++f) {
    m_[f] = -3.0e4f; l_[f] = 0.f;
#pragma unroll
    for (int d4 = 0; d4 < 4; ++d4) o[f][d4] = zero4;
  }

  stage(0, 0);
  __syncthreads();
  int buf = 0;
  const int swz = (lo & 7) << 4;

  for (int t = 0; t < 32; ++t) {
    if (t + 1 < 32) stage(buf ^ 1, t + 1);

    // mask terms for this tile: lane's k = t4*16 + hi*4 + r
    float4 mk4[4];
    const float* mkt = mkrow + t * 64 + hi * 4;
#pragma unroll
    for (int t4 = 0; t4 < 4; ++t4) mk4[t4] = *(const float4*)(mkt + t4 * 16);

    // QK^T swapped: sc[f][t4] rows k = t4*16+hi*4+r, col q = f*16+lo
    const char* kb = (const char*)&Kl[buf][0];
    f32x4 sc[2][4];
#pragma unroll
    for (int t4 = 0; t4 < 4; ++t4) {
      int rb = (t4 * 16 + lo) * 128;
      half8 k0 = *(const half8*)(kb + rb + (((hi) ^ (lo & 7)) << 4));
      half8 k1 = *(const half8*)(kb + rb + (((hi + 4) ^ (lo & 7)) << 4));
#pragma unroll
      for (int f = 0; f < 2; ++f) {
        f32x4 z = __builtin_amdgcn_mfma_f32_16x16x32_f16(k0, qa[f][0], zero4, 0, 0, 0);
        sc[f][t4] = __builtin_amdgcn_mfma_f32_16x16x32_f16(k1, qa[f][1], z, 0, 0, 0);
      }
    }
#pragma unroll
    for (int t4 = 0; t4 < 4; ++t4) {
      float4 mm = mk4[t4];
#pragma unroll
      for (int f = 0; f < 2; ++f) {
        sc[f][t4][0] += mm.x; sc[f][t4][1] += mm.y;
        sc[f][t4][2] += mm.z; sc[f][t4][3] += mm.w;
      }
    }

    // lane-local softmax per frag (lane owns q = f*16+lo; 16 k-values local)
#pragma unroll
    for (int f = 0; f < 2; ++f) {
      float mx = fmaxf(fmaxf(fmaxf(sc[f][0][0], sc[f][0][1]), fmaxf(sc[f][0][2], sc[f][0][3])),
                       fmaxf(fmaxf(sc[f][1][0], sc[f][1][1]), fmaxf(sc[f][1][2], sc[f][1][3])));
      mx = fmaxf(mx, fmaxf(fmaxf(fmaxf(sc[f][2][0], sc[f][2][1]), fmaxf(sc[f][2][2], sc[f][2][3])),
                           fmaxf(fmaxf(sc[f][3][0], sc[f][3][1]), fmaxf(sc[f][3][2], sc[f][3][3]))));
      mx = fmaxf(mx, __shfl_xor(mx, 16));
      mx = fmaxf(mx, __shfl_xor(mx, 32));

      if (!__all(mx <= m_[f] + THR)) {  // defer-max: skip rescale on small growth
        float mn = fmaxf(m_[f], mx);
        float fcv = __builtin_amdgcn_exp2f(m_[f] - mn);
        m_[f] = mn;
        l_[f] *= fcv;
        float fr[4];
#pragma unroll
        for (int r = 0; r < 4; ++r) fr[r] = __shfl(fcv, (hi << 2) + r);
#pragma unroll
        for (int d4 = 0; d4 < 4; ++d4)
#pragma unroll
          for (int r = 0; r < 4; ++r) o[f][d4][r] *= fr[r];
      }

      float rs = 0.f;
#pragma unroll
      for (int t4 = 0; t4 < 4; ++t4) {
#pragma unroll
        for (int r = 0; r < 4; ++r) {
          sc[f][t4][r] = __builtin_amdgcn_exp2f(sc[f][t4][r] - m_[f]);
          rs += sc[f][t4][r];
        }
      }
      rs += __shfl_xor(rs, 16);
      rs += __shfl_xor(rs, 32);
      l_[f] += rs;

      // P -> Pl[q=lo][k], b64 packed (4 consecutive k), XOR-swizzled row
      char* pw = (char*)&Pl[w * 2 + f][0] + lo * 128;
#pragma unroll
      for (int t4 = 0; t4 < 4; ++t4) {
        union { fp16x2 h2[2]; half4_t h4; } u;
        u.h2[0] = __builtin_amdgcn_cvt_pkrtz(sc[f][t4][0], sc[f][t4][1]);
        u.h2[1] = __builtin_amdgcn_cvt_pkrtz(sc[f][t4][2], sc[f][t4][3]);
        *(half4_t*)(pw + ((t4 * 32 + hi * 8) ^ swz)) = u.h4;
      }
    }

    // same-wave LDS RAW fence for P (no barrier needed: Pl is wave-private)
    asm volatile("s_waitcnt lgkmcnt(0)" ::: "memory");
    __builtin_amdgcn_sched_barrier(0);

    // PV: A = P[q][k] (b128 from Pl), B = V[k][d] (= Vl rows, V^T layout)
    const char* vb = (const char*)&Vl[buf][0];
#pragma unroll
    for (int f = 0; f < 2; ++f) {
      const char* pw = (const char*)&Pl[w * 2 + f][0] + lo * 128;
      half8 pa0 = *(const half8*)(pw + ((hi * 16) ^ swz));
      half8 pa1 = *(const half8*)(pw + ((64 + hi * 16) ^ swz));
#pragma unroll
      for (int d4 = 0; d4 < 4; ++d4) {
        int rb = (d4 * 16 + lo) * 128;
        half8 v0 = *(const half8*)(vb + rb + (((hi) ^ (lo & 7)) << 4));
        half8 v1 = *(const half8*)(vb + rb + (((hi + 4) ^ (lo & 7)) << 4));
        o[f][d4] = __builtin_amdgcn_mfma_f32_16x16x32_f16(pa0, v0, o[f][d4], 0, 0, 0);
        o[f][d4] = __builtin_amdgcn_mfma_f32_16x16x32_f16(pa1, v1, o[f][d4], 0, 0, 0);
      }
    }

    __syncthreads();  // drains vmcnt(0): prefetch landed; all waves done reading buf
    buf ^= 1;
  }

  // epilogue: o rows q = f*16 + hi*4 + r, cols d = d4*16 + lo
#pragma unroll
  for (int f = 0; f < 2; ++f) {
    float inv[4];
#pragma unroll
    for (int r = 0; r < 4; ++r) inv[r] = 1.f / __shfl(l_[f], (hi << 2) + r);
#pragma unroll
    for (int r = 0; r < 4; ++r) {
      int q = q0w + f * 16 + (hi << 2) + r;
      float* op = out + ((size_t)(b * 2048) + q) * 768 + h * 64 + lo;
#pragma unroll
      for (int d4 = 0; d4 < 4; ++d4) op[d4 * 16] = o[f][d4][r] * inv[r];
    }
  }
}

extern "C" void kernel_launch(void* const* d_in, const int* in_sizes, int n_in,
                              void* d_out, int out_size, void* d_ws, size_t ws_size,
                              hipStream_t stream) {
  const float* hidden = (const float*)d_in[0];
  const float* mask = (const float*)d_in[1];
  const float* Wq = (const float*)d_in[2];
  const float* bq = (const float*)d_in[3];
  const float* Wk = (const float*)d_in[4];
  const float* bk = (const float*)d_in[5];
  const float* Wv = (const float*)d_in[6];
  const float* bv = (const float*)d_in[7];
  // d_in[8] (head_bias) is constant over the softmax axis -> exactly cancels; unused.
  float* out = (float*)d_out;

  char* ws = (char*)d_ws;
  _Float16* hb   = (_Float16*)(ws);               // [8192][768] f16 (dead after gemm)
  _Float16* wqb  = (_Float16*)(ws + 12582912);
  _Float16* wkb  = (_Float16*)(ws + 13762560);
  _Float16* wvb  = (_Float16*)(ws + 14942208);
  _Float16* qbuf = (_Float16*)(ws + 16121856);    // [48][2048][64]
  _Float16* kbuf = (_Float16*)(ws + 28704768);    // [48][2048][64]
  _Float16* vtb  = (_Float16*)(ws + 41287680);    // [48][64][2048]
  float* mkb     = (float*)(ws);                  // [4][2048] f32, reuses hb region post-gemm

  cvt_f32_f16<<<dim3(1024), dim3(256), 0, stream>>>(hidden, hb, 6291456 / 4);
  cvt_f32_f16<<<dim3(288), dim3(256), 0, stream>>>(Wq, wqb, 589824 / 4);
  cvt_f32_f16<<<dim3(288), dim3(256), 0, stream>>>(Wk, wkb, 589824 / 4);
  cvt_f32_f16<<<dim3(288), dim3(256), 0, stream>>>(Wv, wvb, 589824 / 4);

  qkv_gemm<<<dim3(64, 6, 3), dim3(256), 0, stream>>>(hb, wqb, wkb, wvb, bq, bk, bv,
                                                     qbuf, kbuf, vtb);
  prep_mask<<<dim3(32), dim3(256), 0, stream>>>(mask, mkb, 8192);
  flash_attn<<<dim3(768), dim3(256), 0, stream>>>(qbuf, kbuf, vtb, mkb, out);
}